// Round 6
// baseline (202.319 us; speedup 1.0000x reference)
//
#include <hip/hip_runtime.h>

// B=8, C=128, H=W=64, G=8, K=9, Cg=16, Cd=64. NCHW, HW=4096.
// MFMA conventions (verified in-problem, round 2):
//   A-frag: lane&15 = m, k-octet = (lane>>4)*8 + j
//   B-frag: lane&15 = n, k-octet = (lane>>4)*8 + j
//   C/D:    col = lane&15 (n), row = (lane>>4)*4 + r (m)

typedef __attribute__((ext_vector_type(8))) short short8;
typedef __attribute__((ext_vector_type(4))) float f32x4;
typedef _Float16 __attribute__((ext_vector_type(2))) h2;

static __device__ __forceinline__ unsigned short f2bf(float x) {
    union { float f; unsigned int u; } v; v.f = x;
    return (unsigned short)((v.u + 0x7FFF + ((v.u >> 16) & 1)) >> 16);  // RNE
}
static __device__ __forceinline__ unsigned short f2h(float x) {
    union { _Float16 h; unsigned short u; } v; v.h = (_Float16)x;
    return v.u;
}

// ---------------- feat_s -> pixel-major bf16 fsT + f16 fsH
__global__ __launch_bounds__(256) void k_prepfs(const float* __restrict__ fs,
        uint4* __restrict__ fsT4, uint4* __restrict__ fsH4) {
    __shared__ unsigned short st[64 * 136];
    unsigned int* st32 = (unsigned int*)st;
    const int t = threadIdx.x;
    const int b = blockIdx.x >> 4;
    const int p0 = (blockIdx.x & 15) << 6;
    for (int i = t; i < 64 * 64; i += 256) {
        int c2 = i >> 6, px = i & 63;
        float v0 = fs[(((b << 7) + 2 * c2) << 10) + p0 + px];
        float v1 = fs[(((b << 7) + 2 * c2 + 1) << 10) + p0 + px];
        st32[px * 68 + c2] = (unsigned int)f2bf(v0) | ((unsigned int)f2bf(v1) << 16);
    }
    __syncthreads();
    for (int i = t; i < 64 * 16; i += 256) {
        int px = i >> 4, q = i & 15;
        fsT4[(((b << 10) + p0 + px) << 4) + q] = ((const uint4*)(st + px * 136))[q];
    }
    __syncthreads();
    for (int i = t; i < 64 * 64; i += 256) {
        int c2 = i >> 6, px = i & 63;
        float v0 = fs[(((b << 7) + 2 * c2) << 10) + p0 + px];
        float v1 = fs[(((b << 7) + 2 * c2 + 1) << 10) + p0 + px];
        st32[px * 68 + c2] = (unsigned int)f2h(v0) | ((unsigned int)f2h(v1) << 16);
    }
    __syncthreads();
    for (int i = t; i < 64 * 16; i += 256) {
        int px = i >> 4, q = i & 15;
        fsH4[(((b << 10) + p0 + px) << 4) + q] = ((const uint4*)(st + px * 136))[q];
    }
}

// ---------------- all weight packs in ONE kernel
// segments (uint4 units): wbfsm 2048 | wboff 4096 | wbcat 1024 | wbdcn 9216 (f16!) | wb2 36864
__global__ __launch_bounds__(256) void k_packall(
        const float* __restrict__ W_fsm, const float* __restrict__ W_off,
        const float* __restrict__ W_cat, const float* __restrict__ W_dcn,
        const float* __restrict__ W_om,
        unsigned short* __restrict__ wbfsm, unsigned short* __restrict__ wboff,
        unsigned short* __restrict__ wbcat, unsigned short* __restrict__ wbdcn,
        unsigned short* __restrict__ wb2) {
    int idx = blockIdx.x * 256 + threadIdx.x;
    int lane = idx & 63;
    int ml = lane & 15, kl = (lane >> 4) * 8;
    unsigned short tmp[8];
    if (idx < 2048) {                       // wbfsm: K=128, NT=8 (bf16)
        int r = idx >> 6;
        int o = (r % 8) * 16 + ml, k0 = (r / 8) * 32 + kl;
#pragma unroll
        for (int j = 0; j < 8; j++) tmp[j] = f2bf(W_fsm[o * 128 + k0 + j]);
        ((uint4*)wbfsm)[idx] = *(const uint4*)tmp;
    } else if (idx < 6144) {                // wboff: K=256, NT=8, x2 for k>=128 (bf16)
        int i2 = idx - 2048;
        int r = i2 >> 6;
        int o = (r % 8) * 16 + ml, k0 = (r / 8) * 32 + kl;
#pragma unroll
        for (int j = 0; j < 8; j++) {
            int k = k0 + j;
            float f = W_off[o * 256 + k];
            if (k >= 128) f *= 2.0f;
            tmp[j] = f2bf(f);
        }
        ((uint4*)wboff)[i2] = *(const uint4*)tmp;
    } else if (idx < 7168) {                // wbcat: K=64, NT=8 (bf16)
        int i2 = idx - 6144;
        int r = i2 >> 6;
        int o = (r % 8) * 16 + ml, k0 = (r / 8) * 32 + kl;
#pragma unroll
        for (int j = 0; j < 8; j++) tmp[j] = f2bf(W_cat[o * 64 + k0 + j]);
        ((uint4*)wbcat)[i2] = *(const uint4*)tmp;
    } else if (idx < 16384) {               // wbdcn: K=1152 (g,tap,c), NT=4 (f16)
        int i2 = idx - 7168;
        int r = i2 >> 6;
        int o = (r & 3) * 16 + ml, k0 = (r >> 2) * 32 + kl;
#pragma unroll
        for (int j = 0; j < 8; j++) {
            int k = k0 + j;
            int g = k / 144;
            int rem = k - g * 144;
            tmp[j] = f2h(W_dcn[(o * 128 + g * 16 + (rem & 15)) * 9 + (rem >> 4)]);
        }
        ((uint4*)wbdcn)[i2] = *(const uint4*)tmp;
    } else if (idx < 53248) {               // wb2: K=(tap,c), NT=16 (N=256, pad o>=216) bf16
        int i2 = idx - 16384;
        int r = i2 >> 6;
        int nt = r & 15, kk = r >> 4;
        int tap = kk >> 2, cc = kk & 3;
        int o = nt * 16 + ml;
        int c0 = cc * 32 + kl;
#pragma unroll
        for (int j = 0; j < 8; j++) {
            float v = (o < 216) ? W_om[(o * 128 + (c0 + j)) * 9 + tap] : 0.0f;
            tmp[j] = f2bf(v);
        }
        ((uint4*)wb2)[i2] = *(const uint4*)tmp;
    }
}

// ---------------- k12: fused fsm GEMM (K=128) + off GEMM (K=256)  (round-3, verified)
__global__ __launch_bounds__(256) void k12(const float* __restrict__ feat_l,
        const uint4* __restrict__ fsT4,
        const unsigned short* __restrict__ wbf, const unsigned short* __restrict__ wbo,
        const float* __restrict__ s_fsm, const float* __restrict__ b_fsm,
        const float* __restrict__ s_off, const float* __restrict__ b_off,
        float* __restrict__ feat_arm, unsigned short* __restrict__ offT) {
    __shared__ unsigned short A1[64 * 136];
    __shared__ unsigned short A2[64 * 264];
    float* E32 = (float*)A1;
    const int t = threadIdx.x;
    const int b = blockIdx.x >> 6;
    const int h = blockIdx.x & 63;
    const int hw0 = h << 6;
    unsigned int* A1w = (unsigned int*)A1;
    for (int i = t; i < 64 * 64; i += 256) {
        int c2 = i >> 6, px = i & 63;
        float v0 = feat_l[(((b << 7) + 2 * c2) << 12) + hw0 + px];
        float v1 = feat_l[(((b << 7) + 2 * c2 + 1) << 12) + hw0 + px];
        A1w[px * 68 + c2] = (unsigned int)f2bf(v0) | ((unsigned int)f2bf(v1) << 16);
    }
    {
        const int h2 = h >> 1;
        for (int i = t; i < 32 * 16; i += 256) {
            int px2 = i >> 4, q = i & 15;
            uint4 v = fsT4[(((b << 10) + (h2 << 5) + px2) << 4) + q];
            ((uint4*)(A2 + (2 * px2) * 264 + 128))[q] = v;
            ((uint4*)(A2 + (2 * px2 + 1) * 264 + 128))[q] = v;
        }
    }
    __syncthreads();
    const int lane = t & 63;
    const int wid = __builtin_amdgcn_readfirstlane(t >> 6);
    const int m = lane & 15, ko = lane >> 4;
    f32x4 acc[8];
#pragma unroll
    for (int nt = 0; nt < 8; nt++) acc[nt] = (f32x4){0.f, 0.f, 0.f, 0.f};
#pragma unroll
    for (int kk = 0; kk < 4; kk++) {
        short8 av = *(const short8*)(A1 + (wid * 16 + m) * 136 + kk * 32 + ko * 8);
        const uint4* wb = (const uint4*)wbf + (kk * 8) * 64 + lane;
#pragma unroll
        for (int nt = 0; nt < 8; nt++) {
            uint4 bu = wb[nt * 64];
            acc[nt] = __builtin_amdgcn_mfma_f32_16x16x32_bf16(av, *(short8*)&bu, acc[nt], 0, 0, 0);
        }
    }
#pragma unroll
    for (int nt = 0; nt < 8; nt++) {
        int o = nt * 16 + m;
        float sc = s_fsm[o], bi = b_fsm[o];
#pragma unroll
        for (int r = 0; r < 4; r++) {
            float v = fmaf(acc[nt][r], sc, bi);
            v = v > 0.f ? v : 0.f;
            acc[nt][r] = v;
            A2[(wid * 16 + ko * 4 + r) * 264 + o] = f2bf(v);
        }
    }
#pragma unroll 1
    for (int half = 0; half < 2; half++) {
        __syncthreads();
#pragma unroll
        for (int nt2 = 0; nt2 < 4; nt2++) {
            int nt = half * 4 + nt2;
#pragma unroll
            for (int r = 0; r < 4; r++)
                E32[(wid * 16 + ko * 4 + r) * 67 + nt2 * 16 + m] = acc[nt][r];
        }
        __syncthreads();
        for (int i = t; i < 4096; i += 256) {
            int ol = i >> 6, pp = i & 63;
            feat_arm[(((b << 7) + half * 64 + ol) << 12) + hw0 + pp] = E32[pp * 67 + ol];
        }
    }
    __syncthreads();
    f32x4 acc2[8];
#pragma unroll
    for (int nt = 0; nt < 8; nt++) acc2[nt] = (f32x4){0.f, 0.f, 0.f, 0.f};
#pragma unroll
    for (int kk = 0; kk < 8; kk++) {
        short8 av = *(const short8*)(A2 + (wid * 16 + m) * 264 + kk * 32 + ko * 8);
        const uint4* wb = (const uint4*)wbo + (kk * 8) * 64 + lane;
#pragma unroll
        for (int nt = 0; nt < 8; nt++) {
            uint4 bu = wb[nt * 64];
            acc2[nt] = __builtin_amdgcn_mfma_f32_16x16x32_bf16(av, *(short8*)&bu, acc2[nt], 0, 0, 0);
        }
    }
    __syncthreads();
#pragma unroll
    for (int nt = 0; nt < 8; nt++) {
        int o = nt * 16 + m;
        float sc = s_off[o], bi = b_off[o];
#pragma unroll
        for (int r = 0; r < 4; r++) {
            float v = fmaf(acc2[nt][r], sc, bi);
            v = v > 0.f ? v : 0.f;
            A2[(wid * 16 + ko * 4 + r) * 264 + o] = f2bf(v);
        }
    }
    __syncthreads();
    for (int i = t; i < 64 * 16; i += 256) {
        int px = i >> 4, q = i & 15;
        ((uint4*)offT)[(((b << 12) + hw0 + px) << 4) + q] = ((const uint4*)(A2 + px * 264))[q];
    }
}

// ---------------- k_om v5: barrier-free K-loop implicit-GEMM conv3x3 (round-5, verified)
__global__ __launch_bounds__(256, 3) void k_om(const unsigned short* __restrict__ offT,
        const unsigned short* __restrict__ Wb2, const float* __restrict__ bom,
        float* __restrict__ om) {
    __shared__ unsigned short st[3 * 66 * 136];
    const uint4* offT4 = (const uint4*)offT;
    const uint4* W4 = (const uint4*)Wb2;
    const int t = threadIdx.x;
    const int b = blockIdx.x >> 6;
    const int h = blockIdx.x & 63;
    for (int i = t; i < 3 * 66 * 16; i += 256) {
        int q = i & 15;
        int rp = i >> 4;
        int r = rp / 66, p = rp - r * 66;
        int gy = h + r - 1, gx = p - 1;
        uint4 v = make_uint4(0, 0, 0, 0);
        if (gy >= 0 && gy < 64 && gx >= 0 && gx < 64)
            v = offT4[((((b << 6) + gy) << 6) + gx) * 16 + q];
        ((uint4*)(st + rp * 136))[q] = v;
    }
    __syncthreads();
    const int lane = t & 63;
    const int nh = __builtin_amdgcn_readfirstlane(t >> 6);
    const int m = lane & 15, ko = lane >> 4;
    f32x4 acc[16];
#pragma unroll
    for (int i = 0; i < 16; i++) acc[i] = (f32x4){0.f, 0.f, 0.f, 0.f};
#pragma unroll 4
    for (int kk = 0; kk < 36; kk++) {
        const int tap = kk >> 2, cc = kk & 3;
        const int dy = tap / 3, dx = tap - dy * 3;
        uint4 b4[4];
#pragma unroll
        for (int nt2 = 0; nt2 < 4; nt2++)
            b4[nt2] = W4[(((kk << 4) + (nh << 2) + nt2) << 6) + lane];
        short8 a8[4];
#pragma unroll
        for (int mt = 0; mt < 4; mt++) {
            int p = mt * 16 + m + dx;
            a8[mt] = *(const short8*)(st + (dy * 66 + p) * 136 + (cc << 5) + (ko << 3));
        }
#pragma unroll
        for (int nt2 = 0; nt2 < 4; nt2++)
#pragma unroll
            for (int mt = 0; mt < 4; mt++)
                acc[nt2 * 4 + mt] = __builtin_amdgcn_mfma_f32_16x16x32_bf16(
                    a8[mt], *(short8*)&b4[nt2], acc[nt2 * 4 + mt], 0, 0, 0);
    }
#pragma unroll
    for (int nt2 = 0; nt2 < 4; nt2++) {
        int o = (((nh << 2) + nt2) << 4) + m;
        if (o < 216) {
            float bv = bom[o];
#pragma unroll
            for (int mt = 0; mt < 4; mt++) {
                f32x4 v = acc[nt2 * 4 + mt];
                float4 s = make_float4(v[0] + bv, v[1] + bv, v[2] + bv, v[3] + bv);
                *(float4*)(om + ((b * 216 + o) << 12) + (h << 6) + (mt << 4) + (ko << 2)) = s;
            }
        }
    }
}

// ---------------- k45 v2: DCNv2 sampling in packed f16 + f16 MFMA (4-way K-split) + cat GEMM
// 2048 blocks x 256 thr: block = 16 px; 4 waves = K-quarters (288 each); 8 blocks/CU by LDS.
__global__ __launch_bounds__(256, 5) void k45(const uint4* __restrict__ fsH4,
        const float* __restrict__ om, const unsigned short* __restrict__ wbd,
        const float* __restrict__ bd, const unsigned short* __restrict__ wbc,
        const float* __restrict__ s_cat, const float* __restrict__ b_cat,
        const float* __restrict__ feat_arm, float* __restrict__ feat) {
    __shared__ f32x4 R4[4][4][64];          // 16 KB; reused as T float[128*17]
    __shared__ unsigned short A3[16 * 72];  // align bf16 [px][o]
    const int t = threadIdx.x;
    const int lane = t & 63;
    const int kh = __builtin_amdgcn_readfirstlane(t >> 6);  // K-quarter 0..3
    const int b = blockIdx.x >> 8;
    const int h = (blockIdx.x >> 2) & 63;
    const int q = blockIdx.x & 3;
    const int px0 = q << 4;
    const int m = lane & 15, ko = lane >> 4;
    const int px = px0 + m;
    const int hw = (h << 6) + px;
    const float fh = (float)h, fw = (float)px;
    const int ombase = b * 216 * 4096 + hw;
    const int pb_ = b << 10;
    f32x4 acc[4];
#pragma unroll
    for (int nt = 0; nt < 4; nt++) acc[nt] = (f32x4){0.f, 0.f, 0.f, 0.f};
#pragma unroll 3
    for (int kk = 0; kk < 9; kk++) {
        int k0 = kh * 288 + kk * 32 + ko * 8;
        int g = k0 / 144;
        int rem = k0 - g * 144;
        int tap = rem >> 4;
        int c0 = rem & 15;
        int ch = g * 9 + tap;
        float oy = om[ombase + ch * 4096];
        float ox = om[ombase + (72 + ch) * 4096];
        float mmv = om[ombase + (144 + ch) * 4096];
        mmv = 1.0f / (1.0f + __expf(-mmv));
        float py = fh + (float)(tap / 3 - 1) + oy;
        float pxx = fw + (float)(tap % 3 - 1) + ox;
        float y0f = floorf(py), x0f = floorf(pxx);
        float tyf = py - y0f, txf = pxx - x0f;
        int y0i = (int)y0f, x0i = (int)x0f;
        int y1i = y0i + 1, x1i = x0i + 1;
        bool vy0 = (y0i >= 0) && (y0i < 64);
        bool vy1 = (y1i >= 0) && (y1i < 64);
        bool vx0 = (x0i >= 0) && (x0i < 64);
        bool vx1 = (x1i >= 0) && (x1i < 64);
        float w00 = (vy0 && vx0) ? (1.0f - tyf) * (1.0f - txf) * mmv : 0.0f;
        float w01 = (vy0 && vx1) ? (1.0f - tyf) * txf * mmv : 0.0f;
        float w10 = (vy1 && vx0) ? tyf * (1.0f - txf) * mmv : 0.0f;
        float w11 = (vy1 && vx1) ? tyf * txf * mmv : 0.0f;
        int yc0 = y0i < 0 ? 0 : (y0i > 63 ? 63 : y0i);
        int yc1 = y1i < 0 ? 0 : (y1i > 63 ? 63 : y1i);
        int xc0 = x0i < 0 ? 0 : (x0i > 63 ? 63 : x0i);
        int xc1 = x1i < 0 ? 0 : (x1i > 63 ? 63 : x1i);
        int row0 = (yc0 >> 1) << 5, row1 = (yc1 >> 1) << 5;
        int ci = g * 2 + (c0 >> 3);
        union { uint4 u; h2 h[4]; } C00, C01, C10, C11;
        C00.u = fsH4[((pb_ + row0 + (xc0 >> 1)) << 4) + ci];
        C01.u = fsH4[((pb_ + row0 + (xc1 >> 1)) << 4) + ci];
        C10.u = fsH4[((pb_ + row1 + (xc0 >> 1)) << 4) + ci];
        C11.u = fsH4[((pb_ + row1 + (xc1 >> 1)) << 4) + ci];
        _Float16 h00 = (_Float16)w00, h01 = (_Float16)w01;
        _Float16 h10 = (_Float16)w10, h11 = (_Float16)w11;
        h2 W00 = (h2){h00, h00}, W01 = (h2){h01, h01};
        h2 W10 = (h2){h10, h10}, W11 = (h2){h11, h11};
        union { short8 s; h2 h[4]; } av;
#pragma unroll
        for (int c = 0; c < 4; c++)
            av.h[c] = C00.h[c] * W00 + C01.h[c] * W01 + C10.h[c] * W10 + C11.h[c] * W11;
        const uint4* wb = (const uint4*)wbd + ((kh * 9 + kk) * 4) * 64 + lane;
#pragma unroll
        for (int nt = 0; nt < 4; nt++) {
            uint4 bu = wb[nt * 64];
            acc[nt] = __builtin_amdgcn_mfma_f32_16x16x32_f16(av.s, *(short8*)&bu, acc[nt], 0, 0, 0);
        }
    }
    // all waves write partials; each wave reduces N-tile nt=kh
#pragma unroll
    for (int nt = 0; nt < 4; nt++) R4[kh][nt][lane] = acc[nt];
    __syncthreads();
    {
        f32x4 s = R4[0][kh][lane] + R4[1][kh][lane] + R4[2][kh][lane] + R4[3][kh][lane];
        int o = (kh << 4) + m;
        float bv = bd[o];
#pragma unroll
        for (int r = 0; r < 4; r++) {
            float v = s[r] + bv;
            v = v > 0.f ? v : 0.f;
            A3[((ko << 2) + r) * 72 + o] = f2bf(v);
        }
    }
    __syncthreads();
    // cat GEMM: K=64, N=128; wave kh covers N-tiles 2kh, 2kh+1
    f32x4 acc2[2];
    acc2[0] = (f32x4){0.f, 0.f, 0.f, 0.f};
    acc2[1] = (f32x4){0.f, 0.f, 0.f, 0.f};
#pragma unroll
    for (int kk2 = 0; kk2 < 2; kk2++) {
        short8 av = *(const short8*)(A3 + m * 72 + kk2 * 32 + (ko << 3));
#pragma unroll
        for (int nt2 = 0; nt2 < 2; nt2++) {
            uint4 bu = ((const uint4*)wbc)[(kk2 * 8 + (kh << 1) + nt2) * 64 + lane];
            acc2[nt2] = __builtin_amdgcn_mfma_f32_16x16x32_bf16(av, *(short8*)&bu, acc2[nt2], 0, 0, 0);
        }
    }
    // epilogue via T (overlays R4; R4 reads finished before last barrier)
    float* T = (float*)R4;
#pragma unroll
    for (int nt2 = 0; nt2 < 2; nt2++) {
        int o = ((kh << 1) + nt2) * 16 + m;
        float sc = s_cat[o], bi = b_cat[o];
#pragma unroll
        for (int r = 0; r < 4; r++) {
            float v = fmaf(acc2[nt2][r], sc, bi);
            v = v > 0.f ? v : 0.f;
            T[o * 17 + (ko << 2) + r] = v;
        }
    }
    __syncthreads();
    const int hwbase = (h << 6) + px0;
    for (int i = t; i < 2048; i += 256) {
        int o = i >> 4, pp = i & 15;
        int gidx = (((b << 7) + o) << 12) + hwbase + pp;
        feat[gidx] = T[o * 17 + pp] + feat_arm[gidx];
    }
}

extern "C" void kernel_launch(void* const* d_in, const int* in_sizes, int n_in,
                              void* d_out, int out_size, void* d_ws, size_t ws_size,
                              hipStream_t stream) {
    const float* feat_l = (const float*)d_in[0];
    const float* feat_s = (const float*)d_in[1];
    const float* W_fsm  = (const float*)d_in[2];
    const float* s_fsm  = (const float*)d_in[3];
    const float* b_fsm  = (const float*)d_in[4];
    const float* W_off  = (const float*)d_in[5];
    const float* s_off  = (const float*)d_in[6];
    const float* b_off  = (const float*)d_in[7];
    const float* W_om   = (const float*)d_in[8];
    const float* b_om   = (const float*)d_in[9];
    const float* W_dcn  = (const float*)d_in[10];
    const float* b_dcn  = (const float*)d_in[11];
    const float* W_cat  = (const float*)d_in[12];
    const float* s_cat  = (const float*)d_in[13];
    const float* b_cat  = (const float*)d_in[14];

    float* feat     = (float*)d_out;
    float* feat_arm = feat + 4194304;

    float* ws = (float*)d_ws;
    unsigned short* offT = (unsigned short*)ws;                // 2,097,152 f
    float* om_ws = ws + 2097152;                               // 7,077,888 f
    uint4* fsT4  = (uint4*)(ws + 9175040);                     //   524,288 f
    unsigned short* wb2   = (unsigned short*)(ws + 9699328);   //  147,456 f
    unsigned short* wbfsm = (unsigned short*)(ws + 9846784);   //    8,192 f
    unsigned short* wboff = (unsigned short*)(ws + 9854976);   //   16,384 f
    unsigned short* wbcat = (unsigned short*)(ws + 9871360);   //    4,096 f
    unsigned short* wbdcn = (unsigned short*)(ws + 9875456);   //   36,864 f
    uint4* fsH4  = (uint4*)(ws + 9912320);                     //   524,288 f

    k_prepfs<<<128, 256, 0, stream>>>(feat_s, fsT4, fsH4);
    k_packall<<<208, 256, 0, stream>>>(W_fsm, W_off, W_cat, W_dcn, W_om,
                                       wbfsm, wboff, wbcat, wbdcn, wb2);

    k12<<<512, 256, 0, stream>>>(feat_l, fsT4, wbfsm, wboff,
                                 s_fsm, b_fsm, s_off, b_off, feat_arm, offT);
    k_om<<<512, 256, 0, stream>>>(offT, wb2, b_om, om_ws);
    k45<<<2048, 256, 0, stream>>>(fsH4, om_ws, wbdcn, b_dcn, wbcat,
                                  s_cat, b_cat, feat_arm, feat);
}

// Round 7
// 198.989 us; speedup vs baseline: 1.0167x; 1.0167x over previous
//
#include <hip/hip_runtime.h>

// B=8, C=128, H=W=64, G=8, K=9, Cg=16, Cd=64. NCHW, HW=4096.
// MFMA conventions (verified in-problem, round 2):
//   A-frag: lane&15 = m, k-octet = (lane>>4)*8 + j
//   B-frag: lane&15 = n, k-octet = (lane>>4)*8 + j
//   C/D:    col = lane&15 (n), row = (lane>>4)*4 + r (m)

typedef __attribute__((ext_vector_type(8))) short short8;
typedef __attribute__((ext_vector_type(4))) float f32x4;
typedef _Float16 __attribute__((ext_vector_type(2))) h2;

static __device__ __forceinline__ unsigned short f2bf(float x) {
    union { float f; unsigned int u; } v; v.f = x;
    return (unsigned short)((v.u + 0x7FFF + ((v.u >> 16) & 1)) >> 16);  // RNE
}
static __device__ __forceinline__ unsigned short f2h(float x) {
    union { _Float16 h; unsigned short u; } v; v.h = (_Float16)x;
    return v.u;
}

// ---------------- feat_s -> pixel-major bf16 fsT + f16 fsH
__global__ __launch_bounds__(256) void k_prepfs(const float* __restrict__ fs,
        uint4* __restrict__ fsT4, uint4* __restrict__ fsH4) {
    __shared__ unsigned short st[64 * 136];
    unsigned int* st32 = (unsigned int*)st;
    const int t = threadIdx.x;
    const int b = blockIdx.x >> 4;
    const int p0 = (blockIdx.x & 15) << 6;
    for (int i = t; i < 64 * 64; i += 256) {
        int c2 = i >> 6, px = i & 63;
        float v0 = fs[(((b << 7) + 2 * c2) << 10) + p0 + px];
        float v1 = fs[(((b << 7) + 2 * c2 + 1) << 10) + p0 + px];
        st32[px * 68 + c2] = (unsigned int)f2bf(v0) | ((unsigned int)f2bf(v1) << 16);
    }
    __syncthreads();
    for (int i = t; i < 64 * 16; i += 256) {
        int px = i >> 4, q = i & 15;
        fsT4[(((b << 10) + p0 + px) << 4) + q] = ((const uint4*)(st + px * 136))[q];
    }
    __syncthreads();
    for (int i = t; i < 64 * 64; i += 256) {
        int c2 = i >> 6, px = i & 63;
        float v0 = fs[(((b << 7) + 2 * c2) << 10) + p0 + px];
        float v1 = fs[(((b << 7) + 2 * c2 + 1) << 10) + p0 + px];
        st32[px * 68 + c2] = (unsigned int)f2h(v0) | ((unsigned int)f2h(v1) << 16);
    }
    __syncthreads();
    for (int i = t; i < 64 * 16; i += 256) {
        int px = i >> 4, q = i & 15;
        fsH4[(((b << 10) + p0 + px) << 4) + q] = ((const uint4*)(st + px * 136))[q];
    }
}

// ---------------- all weight packs in ONE kernel
// segments (uint4 units): wbfsm 2048 | wboff 4096 | wbcat 1024 | wbdcn 9216 (f16!) | wb2 36864
__global__ __launch_bounds__(256) void k_packall(
        const float* __restrict__ W_fsm, const float* __restrict__ W_off,
        const float* __restrict__ W_cat, const float* __restrict__ W_dcn,
        const float* __restrict__ W_om,
        unsigned short* __restrict__ wbfsm, unsigned short* __restrict__ wboff,
        unsigned short* __restrict__ wbcat, unsigned short* __restrict__ wbdcn,
        unsigned short* __restrict__ wb2) {
    int idx = blockIdx.x * 256 + threadIdx.x;
    int lane = idx & 63;
    int ml = lane & 15, kl = (lane >> 4) * 8;
    unsigned short tmp[8];
    if (idx < 2048) {                       // wbfsm: K=128, NT=8 (bf16)
        int r = idx >> 6;
        int o = (r % 8) * 16 + ml, k0 = (r / 8) * 32 + kl;
#pragma unroll
        for (int j = 0; j < 8; j++) tmp[j] = f2bf(W_fsm[o * 128 + k0 + j]);
        ((uint4*)wbfsm)[idx] = *(const uint4*)tmp;
    } else if (idx < 6144) {                // wboff: K=256, NT=8, x2 for k>=128 (bf16)
        int i2 = idx - 2048;
        int r = i2 >> 6;
        int o = (r % 8) * 16 + ml, k0 = (r / 8) * 32 + kl;
#pragma unroll
        for (int j = 0; j < 8; j++) {
            int k = k0 + j;
            float f = W_off[o * 256 + k];
            if (k >= 128) f *= 2.0f;
            tmp[j] = f2bf(f);
        }
        ((uint4*)wboff)[i2] = *(const uint4*)tmp;
    } else if (idx < 7168) {                // wbcat: K=64, NT=8 (bf16)
        int i2 = idx - 6144;
        int r = i2 >> 6;
        int o = (r % 8) * 16 + ml, k0 = (r / 8) * 32 + kl;
#pragma unroll
        for (int j = 0; j < 8; j++) tmp[j] = f2bf(W_cat[o * 64 + k0 + j]);
        ((uint4*)wbcat)[i2] = *(const uint4*)tmp;
    } else if (idx < 16384) {               // wbdcn: K=1152 (g,tap,c), NT=4 (f16)
        int i2 = idx - 7168;
        int r = i2 >> 6;
        int o = (r & 3) * 16 + ml, k0 = (r >> 2) * 32 + kl;
#pragma unroll
        for (int j = 0; j < 8; j++) {
            int k = k0 + j;
            int g = k / 144;
            int rem = k - g * 144;
            tmp[j] = f2h(W_dcn[(o * 128 + g * 16 + (rem & 15)) * 9 + (rem >> 4)]);
        }
        ((uint4*)wbdcn)[i2] = *(const uint4*)tmp;
    } else if (idx < 53248) {               // wb2: K=(tap,c), NT=16 (N=256, pad o>=216) bf16
        int i2 = idx - 16384;
        int r = i2 >> 6;
        int nt = r & 15, kk = r >> 4;
        int tap = kk >> 2, cc = kk & 3;
        int o = nt * 16 + ml;
        int c0 = cc * 32 + kl;
#pragma unroll
        for (int j = 0; j < 8; j++) {
            float v = (o < 216) ? W_om[(o * 128 + (c0 + j)) * 9 + tap] : 0.0f;
            tmp[j] = f2bf(v);
        }
        ((uint4*)wb2)[i2] = *(const uint4*)tmp;
    }
}

// ---------------- k12: fused fsm GEMM (K=128) + off GEMM (K=256)  (round-3, verified)
__global__ __launch_bounds__(256) void k12(const float* __restrict__ feat_l,
        const uint4* __restrict__ fsT4,
        const unsigned short* __restrict__ wbf, const unsigned short* __restrict__ wbo,
        const float* __restrict__ s_fsm, const float* __restrict__ b_fsm,
        const float* __restrict__ s_off, const float* __restrict__ b_off,
        float* __restrict__ feat_arm, unsigned short* __restrict__ offT) {
    __shared__ unsigned short A1[64 * 136];
    __shared__ unsigned short A2[64 * 264];
    float* E32 = (float*)A1;
    const int t = threadIdx.x;
    const int b = blockIdx.x >> 6;
    const int h = blockIdx.x & 63;
    const int hw0 = h << 6;
    unsigned int* A1w = (unsigned int*)A1;
    for (int i = t; i < 64 * 64; i += 256) {
        int c2 = i >> 6, px = i & 63;
        float v0 = feat_l[(((b << 7) + 2 * c2) << 12) + hw0 + px];
        float v1 = feat_l[(((b << 7) + 2 * c2 + 1) << 12) + hw0 + px];
        A1w[px * 68 + c2] = (unsigned int)f2bf(v0) | ((unsigned int)f2bf(v1) << 16);
    }
    {
        const int h2 = h >> 1;
        for (int i = t; i < 32 * 16; i += 256) {
            int px2 = i >> 4, q = i & 15;
            uint4 v = fsT4[(((b << 10) + (h2 << 5) + px2) << 4) + q];
            ((uint4*)(A2 + (2 * px2) * 264 + 128))[q] = v;
            ((uint4*)(A2 + (2 * px2 + 1) * 264 + 128))[q] = v;
        }
    }
    __syncthreads();
    const int lane = t & 63;
    const int wid = __builtin_amdgcn_readfirstlane(t >> 6);
    const int m = lane & 15, ko = lane >> 4;
    f32x4 acc[8];
#pragma unroll
    for (int nt = 0; nt < 8; nt++) acc[nt] = (f32x4){0.f, 0.f, 0.f, 0.f};
#pragma unroll
    for (int kk = 0; kk < 4; kk++) {
        short8 av = *(const short8*)(A1 + (wid * 16 + m) * 136 + kk * 32 + ko * 8);
        const uint4* wb = (const uint4*)wbf + (kk * 8) * 64 + lane;
#pragma unroll
        for (int nt = 0; nt < 8; nt++) {
            uint4 bu = wb[nt * 64];
            acc[nt] = __builtin_amdgcn_mfma_f32_16x16x32_bf16(av, *(short8*)&bu, acc[nt], 0, 0, 0);
        }
    }
#pragma unroll
    for (int nt = 0; nt < 8; nt++) {
        int o = nt * 16 + m;
        float sc = s_fsm[o], bi = b_fsm[o];
#pragma unroll
        for (int r = 0; r < 4; r++) {
            float v = fmaf(acc[nt][r], sc, bi);
            v = v > 0.f ? v : 0.f;
            acc[nt][r] = v;
            A2[(wid * 16 + ko * 4 + r) * 264 + o] = f2bf(v);
        }
    }
#pragma unroll 1
    for (int half = 0; half < 2; half++) {
        __syncthreads();
#pragma unroll
        for (int nt2 = 0; nt2 < 4; nt2++) {
            int nt = half * 4 + nt2;
#pragma unroll
            for (int r = 0; r < 4; r++)
                E32[(wid * 16 + ko * 4 + r) * 67 + nt2 * 16 + m] = acc[nt][r];
        }
        __syncthreads();
        for (int i = t; i < 4096; i += 256) {
            int ol = i >> 6, pp = i & 63;
            feat_arm[(((b << 7) + half * 64 + ol) << 12) + hw0 + pp] = E32[pp * 67 + ol];
        }
    }
    __syncthreads();
    f32x4 acc2[8];
#pragma unroll
    for (int nt = 0; nt < 8; nt++) acc2[nt] = (f32x4){0.f, 0.f, 0.f, 0.f};
#pragma unroll
    for (int kk = 0; kk < 8; kk++) {
        short8 av = *(const short8*)(A2 + (wid * 16 + m) * 264 + kk * 32 + ko * 8);
        const uint4* wb = (const uint4*)wbo + (kk * 8) * 64 + lane;
#pragma unroll
        for (int nt = 0; nt < 8; nt++) {
            uint4 bu = wb[nt * 64];
            acc2[nt] = __builtin_amdgcn_mfma_f32_16x16x32_bf16(av, *(short8*)&bu, acc2[nt], 0, 0, 0);
        }
    }
    __syncthreads();
#pragma unroll
    for (int nt = 0; nt < 8; nt++) {
        int o = nt * 16 + m;
        float sc = s_off[o], bi = b_off[o];
#pragma unroll
        for (int r = 0; r < 4; r++) {
            float v = fmaf(acc2[nt][r], sc, bi);
            v = v > 0.f ? v : 0.f;
            A2[(wid * 16 + ko * 4 + r) * 264 + o] = f2bf(v);
        }
    }
    __syncthreads();
    for (int i = t; i < 64 * 16; i += 256) {
        int px = i >> 4, q = i & 15;
        ((uint4*)offT)[(((b << 12) + hw0 + px) << 4) + q] = ((const uint4*)(A2 + px * 264))[q];
    }
}

// ---------------- k_om v5: barrier-free K-loop implicit-GEMM conv3x3 (round-5, verified)
__global__ __launch_bounds__(256, 3) void k_om(const unsigned short* __restrict__ offT,
        const unsigned short* __restrict__ Wb2, const float* __restrict__ bom,
        float* __restrict__ om) {
    __shared__ unsigned short st[3 * 66 * 136];
    const uint4* offT4 = (const uint4*)offT;
    const uint4* W4 = (const uint4*)Wb2;
    const int t = threadIdx.x;
    const int b = blockIdx.x >> 6;
    const int h = blockIdx.x & 63;
    for (int i = t; i < 3 * 66 * 16; i += 256) {
        int q = i & 15;
        int rp = i >> 4;
        int r = rp / 66, p = rp - r * 66;
        int gy = h + r - 1, gx = p - 1;
        uint4 v = make_uint4(0, 0, 0, 0);
        if (gy >= 0 && gy < 64 && gx >= 0 && gx < 64)
            v = offT4[((((b << 6) + gy) << 6) + gx) * 16 + q];
        ((uint4*)(st + rp * 136))[q] = v;
    }
    __syncthreads();
    const int lane = t & 63;
    const int nh = __builtin_amdgcn_readfirstlane(t >> 6);
    const int m = lane & 15, ko = lane >> 4;
    f32x4 acc[16];
#pragma unroll
    for (int i = 0; i < 16; i++) acc[i] = (f32x4){0.f, 0.f, 0.f, 0.f};
#pragma unroll 4
    for (int kk = 0; kk < 36; kk++) {
        const int tap = kk >> 2, cc = kk & 3;
        const int dy = tap / 3, dx = tap - dy * 3;
        uint4 b4[4];
#pragma unroll
        for (int nt2 = 0; nt2 < 4; nt2++)
            b4[nt2] = W4[(((kk << 4) + (nh << 2) + nt2) << 6) + lane];
        short8 a8[4];
#pragma unroll
        for (int mt = 0; mt < 4; mt++) {
            int p = mt * 16 + m + dx;
            a8[mt] = *(const short8*)(st + (dy * 66 + p) * 136 + (cc << 5) + (ko << 3));
        }
#pragma unroll
        for (int nt2 = 0; nt2 < 4; nt2++)
#pragma unroll
            for (int mt = 0; mt < 4; mt++)
                acc[nt2 * 4 + mt] = __builtin_amdgcn_mfma_f32_16x16x32_bf16(
                    a8[mt], *(short8*)&b4[nt2], acc[nt2 * 4 + mt], 0, 0, 0);
    }
#pragma unroll
    for (int nt2 = 0; nt2 < 4; nt2++) {
        int o = (((nh << 2) + nt2) << 4) + m;
        if (o < 216) {
            float bv = bom[o];
#pragma unroll
            for (int mt = 0; mt < 4; mt++) {
                f32x4 v = acc[nt2 * 4 + mt];
                float4 s = make_float4(v[0] + bv, v[1] + bv, v[2] + bv, v[3] + bv);
                *(float4*)(om + ((b * 216 + o) << 12) + (h << 6) + (mt << 4) + (ko << 2)) = s;
            }
        }
    }
}

// ---------------- k45 v3: hoisted om loads (27 in flight) + full unroll + arm prefetch
// 2048 blocks x 256 thr: block = 16 px; 4 waves = K-quarters (288 each).
__global__ __launch_bounds__(256, 4) void k45(const uint4* __restrict__ fsH4,
        const float* __restrict__ om, const unsigned short* __restrict__ wbd,
        const float* __restrict__ bd, const unsigned short* __restrict__ wbc,
        const float* __restrict__ s_cat, const float* __restrict__ b_cat,
        const float* __restrict__ feat_arm, float* __restrict__ feat) {
    __shared__ f32x4 R4[4][4][64];          // 16 KB; reused as T float[128*17]
    __shared__ unsigned short A3[16 * 72];  // align bf16 [px][o]
    const int t = threadIdx.x;
    const int lane = t & 63;
    const int kh = __builtin_amdgcn_readfirstlane(t >> 6);  // K-quarter 0..3
    const int b = blockIdx.x >> 8;
    const int h = (blockIdx.x >> 2) & 63;
    const int q = blockIdx.x & 3;
    const int px0 = q << 4;
    const int m = lane & 15, ko = lane >> 4;
    const int px = px0 + m;
    const int hw = (h << 6) + px;
    const float fh = (float)h, fw = (float)px;
    const int ombase = b * 216 * 4096 + hw;
    const int pb_ = b << 10;
    const int hwbase = (h << 6) + px0;

    // prefetch epilogue feat_arm (independent stream -> free MLP)
    float armv[8];
#pragma unroll
    for (int j = 0; j < 8; j++) {
        int i = t + j * 256;
        int o = i >> 4, pp = i & 15;
        armv[j] = feat_arm[(((b << 7) + o) << 12) + hwbase + pp];
    }

    // hoist ALL om loads: addresses are static -> 27 loads in flight
    float oyv[9], oxv[9], msk[9];
#pragma unroll
    for (int kk = 0; kk < 9; kk++) {
        int k0 = kh * 288 + kk * 32 + ko * 8;
        int g = k0 / 144;
        int rem = k0 - g * 144;
        int ch = g * 9 + (rem >> 4);
        oyv[kk] = om[ombase + ch * 4096];
        oxv[kk] = om[ombase + (72 + ch) * 4096];
        msk[kk] = om[ombase + (144 + ch) * 4096];
    }

    f32x4 acc[4];
#pragma unroll
    for (int nt = 0; nt < 4; nt++) acc[nt] = (f32x4){0.f, 0.f, 0.f, 0.f};
#pragma unroll
    for (int kk = 0; kk < 9; kk++) {
        int k0 = kh * 288 + kk * 32 + ko * 8;
        int g = k0 / 144;
        int rem = k0 - g * 144;
        int tap = rem >> 4;
        int c0 = rem & 15;
        float mmv = 1.0f / (1.0f + __expf(-msk[kk]));
        float py = fh + (float)(tap / 3 - 1) + oyv[kk];
        float pxx = fw + (float)(tap % 3 - 1) + oxv[kk];
        float y0f = floorf(py), x0f = floorf(pxx);
        float tyf = py - y0f, txf = pxx - x0f;
        int y0i = (int)y0f, x0i = (int)x0f;
        int y1i = y0i + 1, x1i = x0i + 1;
        bool vy0 = (y0i >= 0) && (y0i < 64);
        bool vy1 = (y1i >= 0) && (y1i < 64);
        bool vx0 = (x0i >= 0) && (x0i < 64);
        bool vx1 = (x1i >= 0) && (x1i < 64);
        float w00 = (vy0 && vx0) ? (1.0f - tyf) * (1.0f - txf) * mmv : 0.0f;
        float w01 = (vy0 && vx1) ? (1.0f - tyf) * txf * mmv : 0.0f;
        float w10 = (vy1 && vx0) ? tyf * (1.0f - txf) * mmv : 0.0f;
        float w11 = (vy1 && vx1) ? tyf * txf * mmv : 0.0f;
        int yc0 = y0i < 0 ? 0 : (y0i > 63 ? 63 : y0i);
        int yc1 = y1i < 0 ? 0 : (y1i > 63 ? 63 : y1i);
        int xc0 = x0i < 0 ? 0 : (x0i > 63 ? 63 : x0i);
        int xc1 = x1i < 0 ? 0 : (x1i > 63 ? 63 : x1i);
        int row0 = (yc0 >> 1) << 5, row1 = (yc1 >> 1) << 5;
        int ci = g * 2 + (c0 >> 3);
        union { uint4 u; h2 h[4]; } C00, C01, C10, C11;
        C00.u = fsH4[((pb_ + row0 + (xc0 >> 1)) << 4) + ci];
        C01.u = fsH4[((pb_ + row0 + (xc1 >> 1)) << 4) + ci];
        C10.u = fsH4[((pb_ + row1 + (xc0 >> 1)) << 4) + ci];
        C11.u = fsH4[((pb_ + row1 + (xc1 >> 1)) << 4) + ci];
        _Float16 h00 = (_Float16)w00, h01 = (_Float16)w01;
        _Float16 h10 = (_Float16)w10, h11 = (_Float16)w11;
        h2 W00 = (h2){h00, h00}, W01 = (h2){h01, h01};
        h2 W10 = (h2){h10, h10}, W11 = (h2){h11, h11};
        union { short8 s; h2 h[4]; } av;
#pragma unroll
        for (int c = 0; c < 4; c++)
            av.h[c] = C00.h[c] * W00 + C01.h[c] * W01 + C10.h[c] * W10 + C11.h[c] * W11;
        const uint4* wb = (const uint4*)wbd + ((kh * 9 + kk) * 4) * 64 + lane;
#pragma unroll
        for (int nt = 0; nt < 4; nt++) {
            uint4 bu = wb[nt * 64];
            acc[nt] = __builtin_amdgcn_mfma_f32_16x16x32_f16(av.s, *(short8*)&bu, acc[nt], 0, 0, 0);
        }
    }
    // all waves write partials; each wave reduces N-tile nt=kh
#pragma unroll
    for (int nt = 0; nt < 4; nt++) R4[kh][nt][lane] = acc[nt];
    __syncthreads();
    {
        f32x4 s = R4[0][kh][lane] + R4[1][kh][lane] + R4[2][kh][lane] + R4[3][kh][lane];
        int o = (kh << 4) + m;
        float bv = bd[o];
#pragma unroll
        for (int r = 0; r < 4; r++) {
            float v = s[r] + bv;
            v = v > 0.f ? v : 0.f;
            A3[((ko << 2) + r) * 72 + o] = f2bf(v);
        }
    }
    __syncthreads();
    // cat GEMM: K=64, N=128; wave kh covers N-tiles 2kh, 2kh+1
    f32x4 acc2[2];
    acc2[0] = (f32x4){0.f, 0.f, 0.f, 0.f};
    acc2[1] = (f32x4){0.f, 0.f, 0.f, 0.f};
#pragma unroll
    for (int kk2 = 0; kk2 < 2; kk2++) {
        short8 av = *(const short8*)(A3 + m * 72 + kk2 * 32 + (ko << 3));
#pragma unroll
        for (int nt2 = 0; nt2 < 2; nt2++) {
            uint4 bu = ((const uint4*)wbc)[(kk2 * 8 + (kh << 1) + nt2) * 64 + lane];
            acc2[nt2] = __builtin_amdgcn_mfma_f32_16x16x32_bf16(av, *(short8*)&bu, acc2[nt2], 0, 0, 0);
        }
    }
    // epilogue via T (overlays R4)
    float* T = (float*)R4;
#pragma unroll
    for (int nt2 = 0; nt2 < 2; nt2++) {
        int o = ((kh << 1) + nt2) * 16 + m;
        float sc = s_cat[o], bi = b_cat[o];
#pragma unroll
        for (int r = 0; r < 4; r++) {
            float v = fmaf(acc2[nt2][r], sc, bi);
            v = v > 0.f ? v : 0.f;
            T[o * 17 + (ko << 2) + r] = v;
        }
    }
    __syncthreads();
#pragma unroll
    for (int j = 0; j < 8; j++) {
        int i = t + j * 256;
        int o = i >> 4, pp = i & 15;
        feat[(((b << 7) + o) << 12) + hwbase + pp] = T[o * 17 + pp] + armv[j];
    }
}

extern "C" void kernel_launch(void* const* d_in, const int* in_sizes, int n_in,
                              void* d_out, int out_size, void* d_ws, size_t ws_size,
                              hipStream_t stream) {
    const float* feat_l = (const float*)d_in[0];
    const float* feat_s = (const float*)d_in[1];
    const float* W_fsm  = (const float*)d_in[2];
    const float* s_fsm  = (const float*)d_in[3];
    const float* b_fsm  = (const float*)d_in[4];
    const float* W_off  = (const float*)d_in[5];
    const float* s_off  = (const float*)d_in[6];
    const float* b_off  = (const float*)d_in[7];
    const float* W_om   = (const float*)d_in[8];
    const float* b_om   = (const float*)d_in[9];
    const float* W_dcn  = (const float*)d_in[10];
    const float* b_dcn  = (const float*)d_in[11];
    const float* W_cat  = (const float*)d_in[12];
    const float* s_cat  = (const float*)d_in[13];
    const float* b_cat  = (const float*)d_in[14];

    float* feat     = (float*)d_out;
    float* feat_arm = feat + 4194304;

    float* ws = (float*)d_ws;
    unsigned short* offT = (unsigned short*)ws;                // 2,097,152 f
    float* om_ws = ws + 2097152;                               // 7,077,888 f
    uint4* fsT4  = (uint4*)(ws + 9175040);                     //   524,288 f
    unsigned short* wb2   = (unsigned short*)(ws + 9699328);   //  147,456 f
    unsigned short* wbfsm = (unsigned short*)(ws + 9846784);   //    8,192 f
    unsigned short* wboff = (unsigned short*)(ws + 9854976);   //   16,384 f
    unsigned short* wbcat = (unsigned short*)(ws + 9871360);   //    4,096 f
    unsigned short* wbdcn = (unsigned short*)(ws + 9875456);   //   36,864 f
    uint4* fsH4  = (uint4*)(ws + 9912320);                     //   524,288 f

    k_prepfs<<<128, 256, 0, stream>>>(feat_s, fsT4, fsH4);
    k_packall<<<208, 256, 0, stream>>>(W_fsm, W_off, W_cat, W_dcn, W_om,
                                       wbfsm, wboff, wbcat, wbdcn, wb2);

    k12<<<512, 256, 0, stream>>>(feat_l, fsT4, wbfsm, wboff,
                                 s_fsm, b_fsm, s_off, b_off, feat_arm, offT);
    k_om<<<512, 256, 0, stream>>>(offT, wb2, b_om, om_ws);
    k45<<<2048, 256, 0, stream>>>(fsH4, om_ws, wbdcn, b_dcn, wbcat,
                                  s_cat, b_cat, feat_arm, feat);
}

// Round 8
// 188.691 us; speedup vs baseline: 1.0722x; 1.0546x over previous
//
#include <hip/hip_runtime.h>

// B=8, C=128, H=W=64, G=8, K=9, Cg=16, Cd=64. NCHW, HW=4096.
// MFMA conventions (verified in-problem, round 2):
//   A-frag: lane&15 = m, k-octet = (lane>>4)*8 + j
//   B-frag: lane&15 = n, k-octet = (lane>>4)*8 + j
//   C/D:    col = lane&15 (n), row = (lane>>4)*4 + r (m)

typedef __attribute__((ext_vector_type(8))) short short8;
typedef __attribute__((ext_vector_type(4))) float f32x4;
typedef _Float16 __attribute__((ext_vector_type(2))) h2;

static __device__ __forceinline__ unsigned short f2bf(float x) {
    union { float f; unsigned int u; } v; v.f = x;
    return (unsigned short)((v.u + 0x7FFF + ((v.u >> 16) & 1)) >> 16);  // RNE
}
static __device__ __forceinline__ unsigned short f2h(float x) {
    union { _Float16 h; unsigned short u; } v; v.h = (_Float16)x;
    return v.u;
}

// ---------------- feat_s -> pixel-major bf16 fsT + f16 fsH
__global__ __launch_bounds__(256) void k_prepfs(const float* __restrict__ fs,
        uint4* __restrict__ fsT4, uint4* __restrict__ fsH4) {
    __shared__ unsigned short st[64 * 136];
    unsigned int* st32 = (unsigned int*)st;
    const int t = threadIdx.x;
    const int b = blockIdx.x >> 4;
    const int p0 = (blockIdx.x & 15) << 6;
    for (int i = t; i < 64 * 64; i += 256) {
        int c2 = i >> 6, px = i & 63;
        float v0 = fs[(((b << 7) + 2 * c2) << 10) + p0 + px];
        float v1 = fs[(((b << 7) + 2 * c2 + 1) << 10) + p0 + px];
        st32[px * 68 + c2] = (unsigned int)f2bf(v0) | ((unsigned int)f2bf(v1) << 16);
    }
    __syncthreads();
    for (int i = t; i < 64 * 16; i += 256) {
        int px = i >> 4, q = i & 15;
        fsT4[(((b << 10) + p0 + px) << 4) + q] = ((const uint4*)(st + px * 136))[q];
    }
    __syncthreads();
    for (int i = t; i < 64 * 64; i += 256) {
        int c2 = i >> 6, px = i & 63;
        float v0 = fs[(((b << 7) + 2 * c2) << 10) + p0 + px];
        float v1 = fs[(((b << 7) + 2 * c2 + 1) << 10) + p0 + px];
        st32[px * 68 + c2] = (unsigned int)f2h(v0) | ((unsigned int)f2h(v1) << 16);
    }
    __syncthreads();
    for (int i = t; i < 64 * 16; i += 256) {
        int px = i >> 4, q = i & 15;
        fsH4[(((b << 10) + p0 + px) << 4) + q] = ((const uint4*)(st + px * 136))[q];
    }
}

// ---------------- all weight packs in ONE kernel
// segments (uint4 units): wbfsm 2048 | wboff 4096 | wbcat 1024 | wbdcn 9216 (f16!) | wb2 36864
__global__ __launch_bounds__(256) void k_packall(
        const float* __restrict__ W_fsm, const float* __restrict__ W_off,
        const float* __restrict__ W_cat, const float* __restrict__ W_dcn,
        const float* __restrict__ W_om,
        unsigned short* __restrict__ wbfsm, unsigned short* __restrict__ wboff,
        unsigned short* __restrict__ wbcat, unsigned short* __restrict__ wbdcn,
        unsigned short* __restrict__ wb2) {
    int idx = blockIdx.x * 256 + threadIdx.x;
    int lane = idx & 63;
    int ml = lane & 15, kl = (lane >> 4) * 8;
    unsigned short tmp[8];
    if (idx < 2048) {                       // wbfsm: K=128, NT=8 (bf16)
        int r = idx >> 6;
        int o = (r % 8) * 16 + ml, k0 = (r / 8) * 32 + kl;
#pragma unroll
        for (int j = 0; j < 8; j++) tmp[j] = f2bf(W_fsm[o * 128 + k0 + j]);
        ((uint4*)wbfsm)[idx] = *(const uint4*)tmp;
    } else if (idx < 6144) {                // wboff: K=256, NT=8, x2 for k>=128 (bf16)
        int i2 = idx - 2048;
        int r = i2 >> 6;
        int o = (r % 8) * 16 + ml, k0 = (r / 8) * 32 + kl;
#pragma unroll
        for (int j = 0; j < 8; j++) {
            int k = k0 + j;
            float f = W_off[o * 256 + k];
            if (k >= 128) f *= 2.0f;
            tmp[j] = f2bf(f);
        }
        ((uint4*)wboff)[i2] = *(const uint4*)tmp;
    } else if (idx < 7168) {                // wbcat: K=64, NT=8 (bf16)
        int i2 = idx - 6144;
        int r = i2 >> 6;
        int o = (r % 8) * 16 + ml, k0 = (r / 8) * 32 + kl;
#pragma unroll
        for (int j = 0; j < 8; j++) tmp[j] = f2bf(W_cat[o * 64 + k0 + j]);
        ((uint4*)wbcat)[i2] = *(const uint4*)tmp;
    } else if (idx < 16384) {               // wbdcn: K=1152 (g,tap,c), NT=4 (f16)
        int i2 = idx - 7168;
        int r = i2 >> 6;
        int o = (r & 3) * 16 + ml, k0 = (r >> 2) * 32 + kl;
#pragma unroll
        for (int j = 0; j < 8; j++) {
            int k = k0 + j;
            int g = k / 144;
            int rem = k - g * 144;
            tmp[j] = f2h(W_dcn[(o * 128 + g * 16 + (rem & 15)) * 9 + (rem >> 4)]);
        }
        ((uint4*)wbdcn)[i2] = *(const uint4*)tmp;
    } else if (idx < 53248) {               // wb2: K=(tap,c), NT=16 (N=256, pad o>=216) bf16
        int i2 = idx - 16384;
        int r = i2 >> 6;
        int nt = r & 15, kk = r >> 4;
        int tap = kk >> 2, cc = kk & 3;
        int o = nt * 16 + ml;
        int c0 = cc * 32 + kl;
#pragma unroll
        for (int j = 0; j < 8; j++) {
            float v = (o < 216) ? W_om[(o * 128 + (c0 + j)) * 9 + tap] : 0.0f;
            tmp[j] = f2bf(v);
        }
        ((uint4*)wb2)[i2] = *(const uint4*)tmp;
    }
}

// ---------------- k12: fused fsm GEMM (K=128) + off GEMM (K=256)  (round-3, verified)
__global__ __launch_bounds__(256) void k12(const float* __restrict__ feat_l,
        const uint4* __restrict__ fsT4,
        const unsigned short* __restrict__ wbf, const unsigned short* __restrict__ wbo,
        const float* __restrict__ s_fsm, const float* __restrict__ b_fsm,
        const float* __restrict__ s_off, const float* __restrict__ b_off,
        float* __restrict__ feat_arm, unsigned short* __restrict__ offT) {
    __shared__ unsigned short A1[64 * 136];
    __shared__ unsigned short A2[64 * 264];
    float* E32 = (float*)A1;
    const int t = threadIdx.x;
    const int b = blockIdx.x >> 6;
    const int h = blockIdx.x & 63;
    const int hw0 = h << 6;
    unsigned int* A1w = (unsigned int*)A1;
    for (int i = t; i < 64 * 64; i += 256) {
        int c2 = i >> 6, px = i & 63;
        float v0 = feat_l[(((b << 7) + 2 * c2) << 12) + hw0 + px];
        float v1 = feat_l[(((b << 7) + 2 * c2 + 1) << 12) + hw0 + px];
        A1w[px * 68 + c2] = (unsigned int)f2bf(v0) | ((unsigned int)f2bf(v1) << 16);
    }
    {
        const int h2 = h >> 1;
        for (int i = t; i < 32 * 16; i += 256) {
            int px2 = i >> 4, q = i & 15;
            uint4 v = fsT4[(((b << 10) + (h2 << 5) + px2) << 4) + q];
            ((uint4*)(A2 + (2 * px2) * 264 + 128))[q] = v;
            ((uint4*)(A2 + (2 * px2 + 1) * 264 + 128))[q] = v;
        }
    }
    __syncthreads();
    const int lane = t & 63;
    const int wid = __builtin_amdgcn_readfirstlane(t >> 6);
    const int m = lane & 15, ko = lane >> 4;
    f32x4 acc[8];
#pragma unroll
    for (int nt = 0; nt < 8; nt++) acc[nt] = (f32x4){0.f, 0.f, 0.f, 0.f};
#pragma unroll
    for (int kk = 0; kk < 4; kk++) {
        short8 av = *(const short8*)(A1 + (wid * 16 + m) * 136 + kk * 32 + ko * 8);
        const uint4* wb = (const uint4*)wbf + (kk * 8) * 64 + lane;
#pragma unroll
        for (int nt = 0; nt < 8; nt++) {
            uint4 bu = wb[nt * 64];
            acc[nt] = __builtin_amdgcn_mfma_f32_16x16x32_bf16(av, *(short8*)&bu, acc[nt], 0, 0, 0);
        }
    }
#pragma unroll
    for (int nt = 0; nt < 8; nt++) {
        int o = nt * 16 + m;
        float sc = s_fsm[o], bi = b_fsm[o];
#pragma unroll
        for (int r = 0; r < 4; r++) {
            float v = fmaf(acc[nt][r], sc, bi);
            v = v > 0.f ? v : 0.f;
            acc[nt][r] = v;
            A2[(wid * 16 + ko * 4 + r) * 264 + o] = f2bf(v);
        }
    }
#pragma unroll 1
    for (int half = 0; half < 2; half++) {
        __syncthreads();
#pragma unroll
        for (int nt2 = 0; nt2 < 4; nt2++) {
            int nt = half * 4 + nt2;
#pragma unroll
            for (int r = 0; r < 4; r++)
                E32[(wid * 16 + ko * 4 + r) * 67 + nt2 * 16 + m] = acc[nt][r];
        }
        __syncthreads();
        for (int i = t; i < 4096; i += 256) {
            int ol = i >> 6, pp = i & 63;
            feat_arm[(((b << 7) + half * 64 + ol) << 12) + hw0 + pp] = E32[pp * 67 + ol];
        }
    }
    __syncthreads();
    f32x4 acc2[8];
#pragma unroll
    for (int nt = 0; nt < 8; nt++) acc2[nt] = (f32x4){0.f, 0.f, 0.f, 0.f};
#pragma unroll
    for (int kk = 0; kk < 8; kk++) {
        short8 av = *(const short8*)(A2 + (wid * 16 + m) * 264 + kk * 32 + ko * 8);
        const uint4* wb = (const uint4*)wbo + (kk * 8) * 64 + lane;
#pragma unroll
        for (int nt = 0; nt < 8; nt++) {
            uint4 bu = wb[nt * 64];
            acc2[nt] = __builtin_amdgcn_mfma_f32_16x16x32_bf16(av, *(short8*)&bu, acc2[nt], 0, 0, 0);
        }
    }
    __syncthreads();
#pragma unroll
    for (int nt = 0; nt < 8; nt++) {
        int o = nt * 16 + m;
        float sc = s_off[o], bi = b_off[o];
#pragma unroll
        for (int r = 0; r < 4; r++) {
            float v = fmaf(acc2[nt][r], sc, bi);
            v = v > 0.f ? v : 0.f;
            A2[(wid * 16 + ko * 4 + r) * 264 + o] = f2bf(v);
        }
    }
    __syncthreads();
    for (int i = t; i < 64 * 16; i += 256) {
        int px = i >> 4, q = i & 15;
        ((uint4*)offT)[(((b << 12) + hw0 + px) << 4) + q] = ((const uint4*)(A2 + px * 264))[q];
    }
}

// ---------------- k_omdcn: FUSED conv3x3(om) -> LDS -> DCNv2 sample -> cat GEMM -> feat
// 512 blocks (b, row h) x 4 waves.
// Phase 1 (conv): wave = N-quarter nh, acc 16 f32x4 (k_om v5 structure, verified).
// Phase 2: om tile (64 px x 216 ch) + b_om -> LDS (overlay of input stage, barrier-safe).
// Phase 3 (DCN): wave = px-quarter, FULL K=1152; om from LDS, gathers from L2-hot fsH.
// Phase 4: cat GEMM (K=64) + scale/bias/relu + feat_arm add, transposed epilogue.
__global__ __launch_bounds__(256, 2) void k_omdcn(
        const unsigned short* __restrict__ offT, const uint4* __restrict__ fsH4,
        const unsigned short* __restrict__ Wb2, const float* __restrict__ bom,
        const unsigned short* __restrict__ wbd, const float* __restrict__ bd,
        const unsigned short* __restrict__ wbc,
        const float* __restrict__ s_cat, const float* __restrict__ b_cat,
        const float* __restrict__ feat_arm, float* __restrict__ feat) {
    __shared__ float LDSf[16384];                          // 64 KiB
    unsigned short* st = (unsigned short*)LDSf;            // 53,856 B conv input stage
    float* omT = LDSf;                                     // 64*217*4 = 55,552 B (overlay)
    unsigned short* A3 = (unsigned short*)(LDSf + 13888);  // 64*72*2 = 9,216 B (separate)
    float* T = LDSf;                                       // 64*67*4 (overlay, barriered)
    const uint4* offT4 = (const uint4*)offT;
    const uint4* W4 = (const uint4*)Wb2;
    const int t = threadIdx.x;
    const int b = blockIdx.x >> 6;
    const int h = blockIdx.x & 63;
    // ---- stage conv input rows h-1..h+1, 66 px, zero pad
    for (int i = t; i < 3 * 66 * 16; i += 256) {
        int q = i & 15;
        int rp = i >> 4;
        int r = rp / 66, p = rp - r * 66;
        int gy = h + r - 1, gx = p - 1;
        uint4 v = make_uint4(0, 0, 0, 0);
        if (gy >= 0 && gy < 64 && gx >= 0 && gx < 64)
            v = offT4[((((b << 6) + gy) << 6) + gx) * 16 + q];
        ((uint4*)(st + rp * 136))[q] = v;
    }
    __syncthreads();
    const int lane = t & 63;
    const int wid = __builtin_amdgcn_readfirstlane(t >> 6);
    const int m = lane & 15, ko = lane >> 4;
    // ---- phase 1: conv3x3 (wave = N-quarter wid), barrier-free K-loop
    f32x4 acc[16];
#pragma unroll
    for (int i = 0; i < 16; i++) acc[i] = (f32x4){0.f, 0.f, 0.f, 0.f};
#pragma unroll 4
    for (int kk = 0; kk < 36; kk++) {
        const int tap = kk >> 2, cc = kk & 3;
        const int dy = tap / 3, dx = tap - dy * 3;
        uint4 b4[4];
#pragma unroll
        for (int nt2 = 0; nt2 < 4; nt2++)
            b4[nt2] = W4[(((kk << 4) + (wid << 2) + nt2) << 6) + lane];
        short8 a8[4];
#pragma unroll
        for (int mt = 0; mt < 4; mt++) {
            int p = mt * 16 + m + dx;
            a8[mt] = *(const short8*)(st + (dy * 66 + p) * 136 + (cc << 5) + (ko << 3));
        }
#pragma unroll
        for (int nt2 = 0; nt2 < 4; nt2++)
#pragma unroll
            for (int mt = 0; mt < 4; mt++)
                acc[nt2 * 4 + mt] = __builtin_amdgcn_mfma_f32_16x16x32_bf16(
                    a8[mt], *(short8*)&b4[nt2], acc[nt2 * 4 + mt], 0, 0, 0);
    }
    __syncthreads();                       // stage reads done -> omT overlay safe
    // ---- phase 2: om tile -> LDS [px][217]
#pragma unroll
    for (int nt2 = 0; nt2 < 4; nt2++) {
        int o = ((wid * 4 + nt2) << 4) + m;
        if (o < 216) {
            float bv = bom[o];
#pragma unroll
            for (int mt = 0; mt < 4; mt++) {
                f32x4 v = acc[nt2 * 4 + mt];
#pragma unroll
                for (int r = 0; r < 4; r++)
                    omT[(mt * 16 + (ko << 2) + r) * 217 + o] = v[r] + bv;
            }
        }
    }
    __syncthreads();
    // ---- phase 3: DCN sampling, wave = px quarter wid, full K=1152
    const int px = (wid << 4) + m;
    const float fh = (float)h, fw = (float)px;
    const int pb_ = b << 10;
    const float* omrow = omT + px * 217;
    f32x4 accd[4];
#pragma unroll
    for (int nt = 0; nt < 4; nt++) accd[nt] = (f32x4){0.f, 0.f, 0.f, 0.f};
#pragma unroll
    for (int kk = 0; kk < 36; kk++) {
        int k0 = (kk << 5) + (ko << 3);
        int g = k0 / 144;
        int rem = k0 - g * 144;
        int tap = rem >> 4;
        int c0 = rem & 15;
        int ch = g * 9 + tap;
        float oy = omrow[ch];
        float ox = omrow[72 + ch];
        float mmv = omrow[144 + ch];
        mmv = 1.0f / (1.0f + __expf(-mmv));
        float py = fh + (float)(tap / 3 - 1) + oy;
        float pxx = fw + (float)(tap % 3 - 1) + ox;
        float y0f = floorf(py), x0f = floorf(pxx);
        float tyf = py - y0f, txf = pxx - x0f;
        int y0i = (int)y0f, x0i = (int)x0f;
        int y1i = y0i + 1, x1i = x0i + 1;
        bool vy0 = (y0i >= 0) && (y0i < 64);
        bool vy1 = (y1i >= 0) && (y1i < 64);
        bool vx0 = (x0i >= 0) && (x0i < 64);
        bool vx1 = (x1i >= 0) && (x1i < 64);
        float w00 = (vy0 && vx0) ? (1.0f - tyf) * (1.0f - txf) * mmv : 0.0f;
        float w01 = (vy0 && vx1) ? (1.0f - tyf) * txf * mmv : 0.0f;
        float w10 = (vy1 && vx0) ? tyf * (1.0f - txf) * mmv : 0.0f;
        float w11 = (vy1 && vx1) ? tyf * txf * mmv : 0.0f;
        int yc0 = y0i < 0 ? 0 : (y0i > 63 ? 63 : y0i);
        int yc1 = y1i < 0 ? 0 : (y1i > 63 ? 63 : y1i);
        int xc0 = x0i < 0 ? 0 : (x0i > 63 ? 63 : x0i);
        int xc1 = x1i < 0 ? 0 : (x1i > 63 ? 63 : x1i);
        int row0 = (yc0 >> 1) << 5, row1 = (yc1 >> 1) << 5;
        int ci = g * 2 + (c0 >> 3);
        union { uint4 u; h2 h[4]; } C00, C01, C10, C11;
        C00.u = fsH4[((pb_ + row0 + (xc0 >> 1)) << 4) + ci];
        C01.u = fsH4[((pb_ + row0 + (xc1 >> 1)) << 4) + ci];
        C10.u = fsH4[((pb_ + row1 + (xc0 >> 1)) << 4) + ci];
        C11.u = fsH4[((pb_ + row1 + (xc1 >> 1)) << 4) + ci];
        _Float16 h00 = (_Float16)w00, h01 = (_Float16)w01;
        _Float16 h10 = (_Float16)w10, h11 = (_Float16)w11;
        h2 W00 = (h2){h00, h00}, W01 = (h2){h01, h01};
        h2 W10 = (h2){h10, h10}, W11 = (h2){h11, h11};
        union { short8 s; h2 h[4]; } av;
#pragma unroll
        for (int c = 0; c < 4; c++)
            av.h[c] = C00.h[c] * W00 + C01.h[c] * W01 + C10.h[c] * W10 + C11.h[c] * W11;
        const uint4* wb = (const uint4*)wbd + (kk << 2) * 64 + lane;
#pragma unroll
        for (int nt = 0; nt < 4; nt++) {
            uint4 bu = wb[nt * 64];
            accd[nt] = __builtin_amdgcn_mfma_f32_16x16x32_f16(av.s, *(short8*)&bu, accd[nt], 0, 0, 0);
        }
    }
    // ---- phase 4a: align -> A3 bf16 [px][72] (separate LDS region; own-wave RAW only)
#pragma unroll
    for (int nt = 0; nt < 4; nt++) {
        int o = (nt << 4) + m;
        float bv = bd[o];
#pragma unroll
        for (int r = 0; r < 4; r++) {
            float v = accd[nt][r] + bv;
            v = v > 0.f ? v : 0.f;
            A3[((wid << 4) + (ko << 2) + r) * 72 + o] = f2bf(v);
        }
    }
    // ---- phase 4b: cat GEMM K=64, N=128 (wave covers its own 16 px, all 8 N-tiles)
    f32x4 acc2[8];
#pragma unroll
    for (int nt = 0; nt < 8; nt++) acc2[nt] = (f32x4){0.f, 0.f, 0.f, 0.f};
#pragma unroll
    for (int kk2 = 0; kk2 < 2; kk2++) {
        short8 av = *(const short8*)(A3 + ((wid << 4) + m) * 72 + kk2 * 32 + (ko << 3));
#pragma unroll
        for (int nt2 = 0; nt2 < 8; nt2++) {
            uint4 bu = ((const uint4*)wbc)[(kk2 * 8 + nt2) * 64 + lane];
            acc2[nt2] = __builtin_amdgcn_mfma_f32_16x16x32_bf16(av, *(short8*)&bu, acc2[nt2], 0, 0, 0);
        }
    }
    // ---- phase 4c: epilogue, two halves through T (overlays omT; barrier first)
#pragma unroll 1
    for (int half = 0; half < 2; half++) {
        __syncthreads();
#pragma unroll
        for (int nt2l = 0; nt2l < 4; nt2l++) {
            int nt2 = half * 4 + nt2l;
            int o = (nt2 << 4) + m;
            float sc = s_cat[o], bi = b_cat[o];
#pragma unroll
            for (int r = 0; r < 4; r++) {
                float v = fmaf(acc2[nt2][r], sc, bi);
                v = v > 0.f ? v : 0.f;
                T[((wid << 4) + (ko << 2) + r) * 67 + (nt2l << 4) + m] = v;
            }
        }
        __syncthreads();
        for (int i = t; i < 4096; i += 256) {
            int ol = i >> 6, pp = i & 63;
            int gidx = (((b << 7) + half * 64 + ol) << 12) + (h << 6) + pp;
            feat[gidx] = T[pp * 67 + ol] + feat_arm[gidx];
        }
    }
}

extern "C" void kernel_launch(void* const* d_in, const int* in_sizes, int n_in,
                              void* d_out, int out_size, void* d_ws, size_t ws_size,
                              hipStream_t stream) {
    const float* feat_l = (const float*)d_in[0];
    const float* feat_s = (const float*)d_in[1];
    const float* W_fsm  = (const float*)d_in[2];
    const float* s_fsm  = (const float*)d_in[3];
    const float* b_fsm  = (const float*)d_in[4];
    const float* W_off  = (const float*)d_in[5];
    const float* s_off  = (const float*)d_in[6];
    const float* b_off  = (const float*)d_in[7];
    const float* W_om   = (const float*)d_in[8];
    const float* b_om   = (const float*)d_in[9];
    const float* W_dcn  = (const float*)d_in[10];
    const float* b_dcn  = (const float*)d_in[11];
    const float* W_cat  = (const float*)d_in[12];
    const float* s_cat  = (const float*)d_in[13];
    const float* b_cat  = (const float*)d_in[14];

    float* feat     = (float*)d_out;
    float* feat_arm = feat + 4194304;

    float* ws = (float*)d_ws;
    unsigned short* offT = (unsigned short*)ws;                // 2,097,152 f
    uint4* fsT4  = (uint4*)(ws + 9175040);                     //   524,288 f
    unsigned short* wb2   = (unsigned short*)(ws + 9699328);   //  147,456 f
    unsigned short* wbfsm = (unsigned short*)(ws + 9846784);   //    8,192 f
    unsigned short* wboff = (unsigned short*)(ws + 9854976);   //   16,384 f
    unsigned short* wbcat = (unsigned short*)(ws + 9871360);   //    4,096 f
    unsigned short* wbdcn = (unsigned short*)(ws + 9875456);   //   36,864 f
    uint4* fsH4  = (uint4*)(ws + 9912320);                     //   524,288 f

    k_prepfs<<<128, 256, 0, stream>>>(feat_s, fsT4, fsH4);
    k_packall<<<208, 256, 0, stream>>>(W_fsm, W_off, W_cat, W_dcn, W_om,
                                       wbfsm, wboff, wbcat, wbdcn, wb2);

    k12<<<512, 256, 0, stream>>>(feat_l, fsT4, wbfsm, wboff,
                                 s_fsm, b_fsm, s_off, b_off, feat_arm, offT);
    k_omdcn<<<512, 256, 0, stream>>>(offT, fsH4, wb2, b_om, wbdcn, b_dcn,
                                     wbcat, s_cat, b_cat, feat_arm, feat);
}